// Round 2
// baseline (34411.478 us; speedup 1.0000x reference)
//
#include <hip/hip_runtime.h>

#define TT    8192
#define HD    1024
#define NBLK  256       // all blocks are compute blocks now (no sequencer)
#define NTHR  320       // waves 0-3: producers; wave 4: output projector
#define NBUF  4         // pair-ring depth — safety proof below

typedef int i32x4 __attribute__((ext_vector_type(4)));
typedef int i32x2 __attribute__((ext_vector_type(2)));

// ---- LLC-coherent accesses (sc0 sc1 = bypass L1+L2, coherent at MALL) ----
__device__ __forceinline__ void llc_load_pair(const unsigned* p, i32x4& a, i32x4& b) {
  asm volatile("global_load_dwordx4 %0, %2, off sc0 sc1\n\t"
               "global_load_dwordx4 %1, %3, off sc0 sc1\n\t"
               "s_waitcnt vmcnt(0)"
               : "=&v"(a), "=&v"(b)
               : "v"(p), "v"(p + 4)
               : "memory");
}
__device__ __forceinline__ void llc_store2(unsigned* p, unsigned lo, unsigned hi) {
  i32x2 v; v.x = (int)lo; v.y = (int)hi;
  asm volatile("global_store_dwordx2 %0, %1, off sc0 sc1"
               :: "v"(p), "v"(v) : "memory");
}

__device__ __forceinline__ float sigf(float z) {
  return 1.0f / (1.0f + __expf(-z));
}
__device__ __forceinline__ float tanh_fast(float z) {
  float az = fabsf(z);
  float e  = __expf(2.0f * az);          // >= 1
  float t  = 1.0f - 2.0f / (e + 1.0f);
  return z < 0.0f ? -t : t;
}

#define FMA4(acc, hvv, wvv)                                      \
  acc = fmaf((hvv).x, (wvv).x, acc);                             \
  acc = fmaf((hvv).y, (wvv).y, acc);                             \
  acc = fmaf((hvv).z, (wvv).z, acc);                             \
  acc = fmaf((hvv).w, (wvv).w, acc);

// hbuf: unsigned[NBUF][HD][2] {value_bits, tag}; h of step t -> ring t%NBUF,
// tag t+1.  Single 8-B store: tag certifies value (atomic 8-B visibility).
// Consumers SELF-VERIFY: each thread polls the dwordx4 pairs it will consume;
// the load that detects the tag already carries the data (no flag hop, no
// sequencer hop, no second certified load).
//
// RING SAFETY (no flag needed): a producer stores h_t to slot t%4 only after
// its block's poll for h_{t-1} succeeded, i.e. all 1024 units stored h_{t-1},
// i.e. every block finished step t-1, i.e. every block's program-order-earlier
// poll reads of slot t%4 (= step t-3's read of h_{t-4}) completed (each poll
// ends with s_waitcnt vmcnt(0)).  So all reads of the slot precede any
// overwrite.  (Even NBUF=2 satisfies this; NBUF=4 gives 2 extra steps of
// slack.)  QED.
extern "C" __global__ __launch_bounds__(NTHR, 1)
void lstm_persistent(const float* __restrict__ x,
                     const float* __restrict__ W_ih,
                     const float* __restrict__ W_hh,
                     const float* __restrict__ b_ih,
                     const float* __restrict__ b_hh,
                     const float* __restrict__ W_fc,
                     const float* __restrict__ b_fc,
                     float* __restrict__ out,
                     unsigned* __restrict__ hbuf)
{
  const int tid = threadIdx.x;
  const int blk = blockIdx.x;

  __shared__ float x_lds[TT];        // 32 KB: whole input sequence
  __shared__ float h_lds[2][HD];     //  8 KB: double-buffered h broadcast
                                     //  (wave 4 reads parity t&1 concurrently
                                     //   with producers running ahead; the
                                     //   step t+1 barrier orders its step-t
                                     //   read before the step t+2 overwrite)

  const int wave = tid >> 6;
  const int lane = tid & 63;
  const int g    = lane >> 4;        // gate 0..3 (i,f,g,o)
  const int kc   = lane & 15;        // k-chunk within the 1024-dot
  const int unit = blk * 4 + wave;   // valid for waves 0..3 only

  // ---- one-time staging -------------------------------------------------
  for (int i = tid; i < TT / 4; i += NTHR)
    ((float4*)x_lds)[i] = ((const float4*)x)[i];

  float4 w4[16];
  float  wih_g[4], bs_g[4];
  float4 wfc4[4];
  float  bfc_val = 0.0f;

  if (wave < 4) {
    // W_hh row (gate g, unit) — lane covers k = m*64 + kc*4 + {0..3}
    const float* wr = W_hh + (size_t)(g * HD + unit) * HD + kc * 4;
#pragma unroll
    for (int m = 0; m < 16; ++m)
      w4[m] = *((const float4*)(wr + m * 64));
#pragma unroll
    for (int q = 0; q < 4; ++q) {
      int r = q * HD + unit;
      wih_g[q] = W_ih[r];
      bs_g[q]  = b_ih[r] + b_hh[r];
    }
  } else {
    // projector wave: W_fc fragment, lane covers h[m*256 + lane*4 + {0..3}]
#pragma unroll
    for (int m = 0; m < 4; ++m)
      wfc4[m] = *((const float4*)(W_fc + m * 256 + lane * 4));
    bfc_val = b_fc[0];
  }
  float c_state = 0.0f;
  __syncthreads();                   // x_lds ready

  // ---- the sequential scan ---------------------------------------------
  for (int t = 0; t < TT; ++t) {
    float accs = 0.0f;

    if (t > 0) {
      // --- distribute h_{t-1}: direct tag-verified read (single hop) -----
      if (tid < 256) {
        const unsigned* src =
            hbuf + (((t - 1) & (NBUF - 1)) * HD + tid * 4) * 2;
        const int want = t;          // tag of h_{t-1}
        i32x4 A, B;
        do {
          llc_load_pair(src, A, B);
        } while (!(A.y == want && A.w == want && B.y == want && B.w == want));
        float4 hv;
        hv.x = __int_as_float(A.x); hv.y = __int_as_float(A.z);
        hv.z = __int_as_float(B.x); hv.w = __int_as_float(B.z);
        ((float4*)h_lds[t & 1])[tid] = hv;
      }
      __syncthreads();

      if (wave < 4) {
        // fragments + 64 FMAs (4 independent sub-chains)
        const float* hp = h_lds[t & 1] + kc * 4;
        float s0 = 0.f, s1 = 0.f, s2 = 0.f, s3 = 0.f;
#pragma unroll
        for (int mb = 0; mb < 4; ++mb) {
          float4 ha = *((const float4*)(hp + (mb * 4 + 0) * 64));
          float4 hb = *((const float4*)(hp + (mb * 4 + 1) * 64));
          float4 hc = *((const float4*)(hp + (mb * 4 + 2) * 64));
          float4 hd = *((const float4*)(hp + (mb * 4 + 3) * 64));
          FMA4(s0, ha, w4[mb * 4 + 0]);
          FMA4(s1, hb, w4[mb * 4 + 1]);
          FMA4(s2, hc, w4[mb * 4 + 2]);
          FMA4(s3, hd, w4[mb * 4 + 3]);
        }
        accs = (s0 + s1) + (s2 + s3);
      } else if (blk == ((t - 1) & 255)) {
        // --- fused output projection for step t-1, fully OFF the
        //     recurrence critical path (dedicated wave) ------------------
        float p = 0.f;
#pragma unroll
        for (int m = 0; m < 4; ++m) {
          float4 hm = *((const float4*)(h_lds[t & 1] + m * 256 + lane * 4));
          FMA4(p, hm, wfc4[m]);
        }
#pragma unroll
        for (int s = 1; s < 64; s <<= 1) p += __shfl_xor(p, s);
        if (lane == 0) out[t - 1] = p + bfc_val;
      }
    }

    if (wave < 4) {
      // 4-round butterfly over kc: every lane in a gate-group gets the sum
#pragma unroll
      for (int s = 1; s < 16; s <<= 1)
        accs += __shfl_xor(accs, s);

      float gi = __shfl(accs, 0);
      float gf = __shfl(accs, 16);
      float gg = __shfl(accs, 32);
      float go = __shfl(accs, 48);

      if (lane == 0) {
        float xt = x_lds[t];
        gi += fmaf(xt, wih_g[0], bs_g[0]);
        gf += fmaf(xt, wih_g[1], bs_g[1]);
        gg += fmaf(xt, wih_g[2], bs_g[2]);
        go += fmaf(xt, wih_g[3], bs_g[3]);
        c_state  = sigf(gf) * c_state + sigf(gi) * tanh_fast(gg);
        float hn = sigf(go) * tanh_fast(c_state);
        llc_store2(hbuf + (((t & (NBUF - 1)) * HD + unit) * 2),
                   __float_as_uint(hn), (unsigned)(t + 1));  // fire & forget
      }
    }
  }

  // ---- epilogue: out[TT-1] by block 255 (tag-verified direct read) ------
  if (blk == ((TT - 1) & 255)) {
    if (tid < 256) {
      const unsigned* src =
          hbuf + (((TT - 1) & (NBUF - 1)) * HD + tid * 4) * 2;
      i32x4 A, B;
      do {
        llc_load_pair(src, A, B);
      } while (!(A.y == TT && A.w == TT && B.y == TT && B.w == TT));
      float4 hv;
      hv.x = __int_as_float(A.x); hv.y = __int_as_float(A.z);
      hv.z = __int_as_float(B.x); hv.w = __int_as_float(B.z);
      ((float4*)h_lds[0])[tid] = hv;
    }
    __syncthreads();
    if (wave == 4) {
      float p = 0.f;
#pragma unroll
      for (int m = 0; m < 4; ++m) {
        float4 hm = *((const float4*)(h_lds[0] + m * 256 + lane * 4));
        FMA4(p, hm, wfc4[m]);
      }
#pragma unroll
      for (int s = 1; s < 64; s <<= 1) p += __shfl_xor(p, s);
      if (lane == 0) out[TT - 1] = p + bfc_val;
    }
  }
}

extern "C" void kernel_launch(void* const* d_in, const int* in_sizes, int n_in,
                              void* d_out, int out_size, void* d_ws, size_t ws_size,
                              hipStream_t stream) {
  const float* x   = (const float*)d_in[0];
  const float* Wih = (const float*)d_in[1];
  const float* Whh = (const float*)d_in[2];
  const float* bih = (const float*)d_in[3];
  const float* bhh = (const float*)d_in[4];
  const float* Wfc = (const float*)d_in[5];
  const float* bfc = (const float*)d_in[6];
  float* out = (float*)d_out;

  // ws layout: [hbuf: NBUF*HD tagged pairs = 32 KB]
  unsigned* hbuf = (unsigned*)d_ws;
  size_t init_bytes = (size_t)(NBUF * HD * 2) * sizeof(unsigned);

  // zeros: tag 0 never equals any expected tag (>=1)
  hipMemsetAsync(d_ws, 0, init_bytes, stream);
  hipLaunchKernelGGL(lstm_persistent, dim3(NBLK), dim3(NTHR), 0, stream,
                     x, Wih, Whh, bih, bhh, Wfc, bfc, out, hbuf);
}